// Round 16
// baseline (315.900 us; speedup 1.0000x reference)
//
#include <hip/hip_runtime.h>

#define EPS 1e-5f
#define APITCH 264   // bf16 tile row pitch (shorts); 528B rows, 16B-aligned

typedef __attribute__((ext_vector_type(8))) short bf16x8;
typedef __attribute__((ext_vector_type(4))) float f32x4;
typedef __attribute__((ext_vector_type(2))) float f32x2;

// RTNE (one-time weight conversion)
__device__ __forceinline__ unsigned short f2b_rtne(float f) {
  unsigned u = __builtin_bit_cast(unsigned, f);
  u += 0x7fffu + ((u >> 16) & 1u);
  return (unsigned short)(u >> 16);
}
// HW packed f32->2xbf16 (RTNE)
__device__ __forceinline__ unsigned cvt_pk(float lo, float hi) {
  unsigned r;
  asm("v_cvt_pk_bf16_f32 %0, %1, %2" : "=v"(r) : "v"(lo), "v"(hi));
  return r;
}
__device__ __forceinline__ float bhalf(unsigned pk, int hi) {
  unsigned u = hi ? (pk & 0xffff0000u) : (pk << 16);
  return __builtin_bit_cast(float, u);
}
__device__ __forceinline__ int div9(int r) {
  return (int)(__umulhi((unsigned)r, 954437177u) >> 1);
}

// ---- packed f32 math (CDNA dual-FP32 VOP3P) ----
__device__ __forceinline__ f32x2 pk_add(f32x2 a, f32x2 b) {
  f32x2 d; asm("v_pk_add_f32 %0, %1, %2" : "=v"(d) : "v"(a), "v"(b)); return d;
}
__device__ __forceinline__ f32x2 pk_mul(f32x2 a, f32x2 b) {
  f32x2 d; asm("v_pk_mul_f32 %0, %1, %2" : "=v"(d) : "v"(a), "v"(b)); return d;
}
__device__ __forceinline__ f32x2 pk_fma(f32x2 a, f32x2 b, f32x2 c) {
  f32x2 d; asm("v_pk_fma_f32 %0, %1, %2, %3" : "=v"(d) : "v"(a), "v"(b), "v"(c)); return d;
}
__device__ __forceinline__ f32x2 ld2(const float* p) { return *(const f32x2*)p; }

// ---- DPP 16-lane sum reduction (ctrl is a template literal) ----
template <int CTRL>
__device__ __forceinline__ float dppadd(float v) {
  int x = __builtin_amdgcn_update_dpp(0, __builtin_bit_cast(int, v), CTRL, 0xf, 0xf, true);
  return v + __builtin_bit_cast(float, x);
}
__device__ __forceinline__ float dpp_reduce16(float v) {
  v = dppadd<0xB1>(v);    // quad_perm:[1,0,3,2]  (xor 1)
  v = dppadd<0x4E>(v);    // quad_perm:[2,3,0,1]  (xor 2)
  v = dppadd<0x124>(v);   // row_ror:4
  v = dppadd<0x128>(v);   // row_ror:8
  return v;               // every lane in the 16-lane row holds the row sum
}

// Convert all 5 weight matrices into MFMA-fragment-linear bf16 (contiguous dst).
// ig/ug/fc k-index pre-permuted for the pi-packed LDS tiles:
//   pi: col = cb + q*16 + lr  ->  p = cb + lr*4 + q  (within each 64-col block)
__global__ void k_cvt_all(const float* __restrict__ dynW, const float* __restrict__ inpW,
                          const float* __restrict__ igW, const float* __restrict__ ugW,
                          const float* __restrict__ fcW, unsigned short* __restrict__ dst) {
  int i = blockIdx.x * blockDim.x + threadIdx.x;   // [0, 458752)
  const float* src; int off; int perm;
  if (i < 131072)      { src = dynW; off = i;          perm = 0; }
  else if (i < 262144) { src = inpW; off = i - 131072; perm = 0; }
  else if (i < 327680) { src = igW;  off = i - 262144; perm = 1; }
  else if (i < 393216) { src = ugW;  off = i - 327680; perm = 1; }
  else                 { src = fcW;  off = i - 393216; perm = 1; }
  int j = off & 7, lane = (off >> 3) & 63, kk = (off >> 9) & 7, ct = off >> 12;
  int row = ct * 16 + (lane & 15);
  int p = kk * 32 + (lane >> 4) * 8 + j;           // k position in fragment order
  int col = perm ? ((p & ~63) + (p & 3) * 16 + ((p >> 2) & 15)) : p;
  dst[i] = f2b_rtne(src[row * 256 + col]);
}

// ================= 32-row main kernel: a-frags HELD across phase pairs =================
// R16 change vs R15: a[2][8] loaded ONCE per tile-source (PH0+PH1 share aT;
// PH2+PH3 share gT; PH4 reloads features-aT) -> LDS a-reads 320 -> 48 b128/wave.
// b[8] streamed per q unchanged (R10: splitting the burst = -33%).

__device__ __forceinline__ void loadA2(const short* src, bf16x8 (&a)[2][8],
                                       int lr, int lh) {
#pragma unroll
  for (int kk = 0; kk < 8; kk++) {
    a[0][kk] = *(const bf16x8*)&src[lr * APITCH + kk * 32 + lh * 8];
    a[1][kk] = *(const bf16x8*)&src[(16 + lr) * APITCH + kk * 32 + lh * 8];
  }
}

__device__ __forceinline__ void gemmQh(const bf16x8 (&a)[2][8],
                                       const unsigned short* __restrict__ W,
                                       f32x4 (&acc)[4][2], int wv, int lane) {
#pragma unroll
  for (int q = 0; q < 4; q++) {
    const unsigned short* Wp = W + ((wv * 4 + q) << 12) + lane * 8;
    bf16x8 b[8];
#pragma unroll
    for (int kk = 0; kk < 8; kk++) b[kk] = *(const bf16x8*)&Wp[kk * 512];
    acc[q][0] = (f32x4){0.f, 0.f, 0.f, 0.f};
    acc[q][1] = (f32x4){0.f, 0.f, 0.f, 0.f};
#pragma unroll
    for (int kk = 0; kk < 8; kk++) {
      acc[q][0] = __builtin_amdgcn_mfma_f32_16x16x32_bf16(a[0][kk], b[kk], acc[q][0], 0, 0, 0);
      acc[q][1] = __builtin_amdgcn_mfma_f32_16x16x32_bf16(a[1][kk], b[kk], acc[q][1], 0, 0, 0);
    }
  }
}

// per-row (sum, sumsq): pk presum over q, DPP 16-lane reduce, one LDS write per row-pair
__device__ __forceinline__ void statsW(const f32x4 (&acc)[4][2], const f32x2 (&b42)[4],
                                       float* sP, float* qP, int wv, int lr, int lh) {
#pragma unroll
  for (int rh = 0; rh < 2; rh++)
#pragma unroll
    for (int p = 0; p < 2; p++) {
      f32x2 s2 = (f32x2){0.f, 0.f}, q2 = (f32x2){0.f, 0.f};
#pragma unroll
      for (int q = 0; q < 4; q++) {
        f32x2 a2 = (f32x2){acc[q][rh][2 * p], acc[q][rh][2 * p + 1]};
        f32x2 t = pk_add(a2, b42[q]);
        s2 = pk_add(s2, t);
        q2 = pk_fma(t, t, q2);
      }
      float s0 = dpp_reduce16(s2[0]);
      float s1 = dpp_reduce16(s2[1]);
      float q0 = dpp_reduce16(q2[0]);
      float q1 = dpp_reduce16(q2[1]);
      if (lr == 0) {
        int r = rh * 16 + lh * 4 + 2 * p;
        sP[wv * 32 + r] = s0;  sP[wv * 32 + r + 1] = s1;
        qP[wv * 32 + r] = q0;  qP[wv * 32 + r + 1] = q1;
      }
    }
}
// cross-wave combine -> (-mu, rs) pairs
__device__ __forceinline__ void statsR(const float* sP, const float* qP,
                                       f32x2 (&nmu)[2][2], f32x2 (&rv)[2][2], int lh) {
#pragma unroll
  for (int rh = 0; rh < 2; rh++)
#pragma unroll
    for (int p = 0; p < 2; p++) {
      int r = rh * 16 + lh * 4 + 2 * p;
      f32x2 S = pk_add(pk_add(ld2(sP + r), ld2(sP + 32 + r)),
                       pk_add(ld2(sP + 64 + r), ld2(sP + 96 + r)));
      f32x2 Q = pk_add(pk_add(ld2(qP + r), ld2(qP + 32 + r)),
                       pk_add(ld2(qP + 64 + r), ld2(qP + 96 + r)));
      float m0 = S[0] * (1.f / 256.f), m1 = S[1] * (1.f / 256.f);
      nmu[rh][p] = (f32x2){-m0, -m1};
      rv[rh][p] = (f32x2){rsqrtf(Q[0] * (1.f / 256.f) - m0 * m0 + EPS),
                          rsqrtf(Q[1] * (1.f / 256.f) - m1 * m1 + EPS)};
    }
}

// NOTE: no min-waves arg — a second __launch_bounds__ argument caps arch-VGPR at
// 256/minwaves on MFMA kernels (observed R2-R4) and forces scratch.
__global__ __launch_bounds__(256) void k_main(
    const float* __restrict__ inf,
    const unsigned short* __restrict__ inpWf, const float* __restrict__ inpb,
    const unsigned short* __restrict__ igWf, const float* __restrict__ igb,
    const unsigned short* __restrict__ ugWf, const float* __restrict__ ugb,
    const unsigned short* __restrict__ fcWf, const float* __restrict__ fcb,
    const float* __restrict__ nig, const float* __restrict__ nib,
    const float* __restrict__ iig, const float* __restrict__ iib,
    const float* __restrict__ iog, const float* __restrict__ iob,
    const float* __restrict__ fng, const float* __restrict__ fnb,
    const float* __restrict__ param_in, const float* __restrict__ param_out_ln,
    float* __restrict__ out) {
  __shared__ short aT[32 * APITCH];
  __shared__ short gT[32 * APITCH];
  __shared__ float sP[2][128], qP[2][128];

  const int t = threadIdx.x;
  const int wv = t >> 6, lane = t & 63, lr = lane & 15, lh = lane >> 4;
  const int cb = wv * 64;
  const int r0 = blockIdx.x * 32;

  // stage 32x256 f32 -> bf16 LDS (coalesced float4 in, packed b64 out)
#pragma unroll
  for (int j = 0; j < 8; j++) {
    const int idx4 = j * 256 + t;
    const int row = idx4 >> 6;
    const int c4 = (idx4 & 63) << 2;
    const float4 v = *(const float4*)&inf[(size_t)(r0 + row) * 256 + c4];
    uint2 pk;
    pk.x = cvt_pk(v.x, v.y);
    pk.y = cvt_pk(v.z, v.w);
    *(uint2*)&aT[row * APITCH + c4] = pk;
  }
  __syncthreads();                              // S1

  bf16x8 a[2][8];
  f32x4 acc[4][2];
  f32x2 b42[4], ga2[4], be2[4], nmu[2][2], rv[2][2];
  unsigned gio[4][2][2];   // packed bf16 pairs per (q, pair)

  loadA2(aT, a, lr, lh);   // a held across PH0 + PH1

  // ---- PH0: input_in -> gate_feats -> gT (pi-layout, packed 8B writes) ----
  gemmQh(a, inpWf, acc, wv, lane);
#pragma unroll
  for (int q = 0; q < 4; q++) { float b = inpb[cb + q * 16 + lr]; b42[q] = (f32x2){b, b}; }
#pragma unroll
  for (int rh = 0; rh < 2; rh++)
#pragma unroll
    for (int p = 0; p < 2; p++) {
      const int rrA = rh * 16 + lh * 4 + 2 * p;
      const float* pin0 = param_in + (size_t)div9(r0 + rrA) * 256;
      const float* pin1 = param_in + (size_t)div9(r0 + rrA + 1) * 256;
      float gAv[4], gBv[4];
#pragma unroll
      for (int q = 0; q < 4; q++) {
        f32x2 a2 = (f32x2){acc[q][rh][2 * p], acc[q][rh][2 * p + 1]};
        f32x2 tt = pk_add(a2, b42[q]);
        gAv[q] = tt[0] * pin0[cb + q * 16 + lr];
        gBv[q] = tt[1] * pin1[cb + q * 16 + lr];
      }
      uint2 pkA, pkB;
      pkA.x = cvt_pk(gAv[0], gAv[1]); pkA.y = cvt_pk(gAv[2], gAv[3]);
      pkB.x = cvt_pk(gBv[0], gBv[1]); pkB.y = cvt_pk(gBv[2], gBv[3]);
      *(uint2*)&gT[rrA * APITCH + cb + lr * 4] = pkA;
      *(uint2*)&gT[(rrA + 1) * APITCH + cb + lr * 4] = pkB;
    }

  // ---- PH1: input_out (same a), LN -> gio ----
  gemmQh(a, inpWf + (16 << 12), acc, wv, lane);
#pragma unroll
  for (int q = 0; q < 4; q++) { float b = inpb[256 + cb + q * 16 + lr]; b42[q] = (f32x2){b, b}; }
  statsW(acc, b42, sP[1], qP[1], wv, lr, lh);
  __syncthreads();                              // S2: gT + stats published
  statsR(sP[1], qP[1], nmu, rv, lh);
#pragma unroll
  for (int q = 0; q < 4; q++) {
    float g = iog[cb + q * 16 + lr], e = iob[cb + q * 16 + lr];
    ga2[q] = (f32x2){g, g}; be2[q] = (f32x2){e, e};
  }
#pragma unroll
  for (int q = 0; q < 4; q++)
#pragma unroll
    for (int rh = 0; rh < 2; rh++)
#pragma unroll
      for (int p = 0; p < 2; p++) {
        f32x2 a2 = (f32x2){acc[q][rh][2 * p], acc[q][rh][2 * p + 1]};
        f32x2 tt = pk_add(pk_add(a2, b42[q]), nmu[rh][p]);
        f32x2 v2 = pk_fma(pk_mul(tt, rv[rh][p]), ga2[q], be2[q]);
        gio[q][rh][p] = cvt_pk(v2[0], v2[1]);
      }

  loadA2(gT, a, lr, lh);   // a held across PH2 + PH3

  // ---- PH2: ig gate on gT; gio <- g1 * ioLN ----
  gemmQh(a, igWf, acc, wv, lane);
#pragma unroll
  for (int q = 0; q < 4; q++) { float b = igb[cb + q * 16 + lr]; b42[q] = (f32x2){b, b}; }
  statsW(acc, b42, sP[0], qP[0], wv, lr, lh);
  __syncthreads();                              // S3
  statsR(sP[0], qP[0], nmu, rv, lh);
#pragma unroll
  for (int q = 0; q < 4; q++) {
    float g = iig[cb + q * 16 + lr], e = iib[cb + q * 16 + lr];
    ga2[q] = (f32x2){g, g}; be2[q] = (f32x2){e, e};
  }
#pragma unroll
  for (int q = 0; q < 4; q++)
#pragma unroll
    for (int rh = 0; rh < 2; rh++)
#pragma unroll
      for (int p = 0; p < 2; p++) {
        f32x2 a2 = (f32x2){acc[q][rh][2 * p], acc[q][rh][2 * p + 1]};
        f32x2 tt = pk_add(pk_add(a2, b42[q]), nmu[rh][p]);
        f32x2 p2 = pk_fma(pk_mul(tt, rv[rh][p]), ga2[q], be2[q]);
        float g10 = 1.f / (1.f + __expf(-p2[0]));
        float g11 = 1.f / (1.f + __expf(-p2[1]));
        unsigned w = gio[q][rh][p];
        gio[q][rh][p] = cvt_pk(g10 * bhalf(w, 0), g11 * bhalf(w, 1));
      }

  // ---- PH3: ug gate (same a); features = g2*param_out_ln + gio -> aT (pi) ----
  gemmQh(a, ugWf, acc, wv, lane);
#pragma unroll
  for (int q = 0; q < 4; q++) { float b = ugb[cb + q * 16 + lr]; b42[q] = (f32x2){b, b}; }
  statsW(acc, b42, sP[1], qP[1], wv, lr, lh);
  __syncthreads();                              // S4
  statsR(sP[1], qP[1], nmu, rv, lh);
#pragma unroll
  for (int q = 0; q < 4; q++) {
    float g = nig[cb + q * 16 + lr], e = nib[cb + q * 16 + lr];
    ga2[q] = (f32x2){g, g}; be2[q] = (f32x2){e, e};
  }
#pragma unroll
  for (int rh = 0; rh < 2; rh++)
#pragma unroll
    for (int p = 0; p < 2; p++) {
      const int rrA = rh * 16 + lh * 4 + 2 * p;
      const float* po0 = param_out_ln + (size_t)div9(r0 + rrA) * 256;
      const float* po1 = param_out_ln + (size_t)div9(r0 + rrA + 1) * 256;
      float fA[4], fB[4];
#pragma unroll
      for (int q = 0; q < 4; q++) {
        f32x2 a2 = (f32x2){acc[q][rh][2 * p], acc[q][rh][2 * p + 1]};
        f32x2 tt = pk_add(pk_add(a2, b42[q]), nmu[rh][p]);
        f32x2 u2 = pk_fma(pk_mul(tt, rv[rh][p]), ga2[q], be2[q]);
        float g20 = 1.f / (1.f + __expf(-u2[0]));
        float g21 = 1.f / (1.f + __expf(-u2[1]));
        unsigned w = gio[q][rh][p];
        fA[q] = g20 * po0[cb + q * 16 + lr] + bhalf(w, 0);
        fB[q] = g21 * po1[cb + q * 16 + lr] + bhalf(w, 1);
      }
      uint2 pkA, pkB;
      pkA.x = cvt_pk(fA[0], fA[1]); pkA.y = cvt_pk(fA[2], fA[3]);
      pkB.x = cvt_pk(fB[0], fB[1]); pkB.y = cvt_pk(fB[2], fB[3]);
      *(uint2*)&aT[rrA * APITCH + cb + lr * 4] = pkA;
      *(uint2*)&aT[(rrA + 1) * APITCH + cb + lr * 4] = pkB;
    }
  __syncthreads();                              // S5: features published in aT

  // ---- PH4: fc (pi-permuted weights), LN, relu -> out ----
  loadA2(aT, a, lr, lh);
  gemmQh(a, fcWf, acc, wv, lane);
#pragma unroll
  for (int q = 0; q < 4; q++) { float b = fcb[cb + q * 16 + lr]; b42[q] = (f32x2){b, b}; }
  statsW(acc, b42, sP[0], qP[0], wv, lr, lh);
  __syncthreads();                              // S6
  statsR(sP[0], qP[0], nmu, rv, lh);
#pragma unroll
  for (int q = 0; q < 4; q++) {
    float g = fng[cb + q * 16 + lr], e = fnb[cb + q * 16 + lr];
    ga2[q] = (f32x2){g, g}; be2[q] = (f32x2){e, e};
  }
#pragma unroll
  for (int q = 0; q < 4; q++) {
    const int col = cb + q * 16 + lr;
#pragma unroll
    for (int rh = 0; rh < 2; rh++)
#pragma unroll
      for (int p = 0; p < 2; p++) {
        f32x2 a2 = (f32x2){acc[q][rh][2 * p], acc[q][rh][2 * p + 1]};
        f32x2 tt = pk_add(pk_add(a2, b42[q]), nmu[rh][p]);
        f32x2 v2 = pk_fma(pk_mul(tt, rv[rh][p]), ga2[q], be2[q]);
        const int rrA = r0 + rh * 16 + lh * 4 + 2 * p;
        out[(size_t)rrA * 256 + col] = fmaxf(v2[0], 0.f);
        out[(size_t)(rrA + 1) * 256 + col] = fmaxf(v2[1], 0.f);
      }
  }
}

// ================= kernel 1: params (unchanged) =================
#define FPITCH 516

__device__ __forceinline__ void red8(float& s, float& q) {
#pragma unroll
  for (int m = 1; m < 8; m <<= 1) { s += __shfl_xor(s, m); q += __shfl_xor(q, m); }
}

__global__ __launch_bounds__(256) void k_params(
    const float* __restrict__ uf, const unsigned short* __restrict__ dynWf,
    const float* __restrict__ dynb, const float* __restrict__ nog,
    const float* __restrict__ nob, float* __restrict__ param_in,
    float* __restrict__ param_out_ln) {
  __shared__ short aT[32 * APITCH];
  __shared__ float fBuf[32 * FPITCH];
  const int t = threadIdx.x;
  const int wv = t >> 6, lane = t & 63, lr = lane & 15, lh = lane >> 4;
  const int r0 = blockIdx.x * 32;
#pragma unroll
  for (int j = 0; j < 8; j++) {
    const int idx4 = j * 256 + t;
    const int row = idx4 >> 6;
    const int c4 = (idx4 & 63) << 2;
    const float4 v = *(const float4*)&uf[(size_t)(r0 + row) * 256 + c4];
    uint2 pk;
    pk.x = cvt_pk(v.x, v.y);
    pk.y = cvt_pk(v.z, v.w);
    *(uint2*)&aT[row * APITCH + c4] = pk;
  }
  __syncthreads();
  bf16x8 a0[8], a1[8];
#pragma unroll
  for (int kk = 0; kk < 8; kk++) {
    a0[kk] = *(const bf16x8*)&aT[lr * APITCH + kk * 32 + lh * 8];
    a1[kk] = *(const bf16x8*)&aT[(16 + lr) * APITCH + kk * 32 + lh * 8];
  }
#pragma unroll 1
  for (int cp = 0; cp < 8; cp++) {
    const int ct = wv * 8 + cp;
    bf16x8 b[8];
#pragma unroll
    for (int kk = 0; kk < 8; kk++)
      b[kk] = *(const bf16x8*)&dynWf[((ct * 8 + kk) * 64 + lane) * 8];
    const float bi = dynb[ct * 16 + lr];
    f32x4 c0 = {0.f, 0.f, 0.f, 0.f}, c1 = c0;
#pragma unroll
    for (int kk = 0; kk < 8; kk++) {
      c0 = __builtin_amdgcn_mfma_f32_16x16x32_bf16(a0[kk], b[kk], c0, 0, 0, 0);
      c1 = __builtin_amdgcn_mfma_f32_16x16x32_bf16(a1[kk], b[kk], c1, 0, 0, 0);
    }
#pragma unroll
    for (int i = 0; i < 4; i++) {
      fBuf[(lh * 4 + i) * FPITCH + ct * 16 + lr] = c0[i] + bi;
      fBuf[(16 + lh * 4 + i) * FPITCH + ct * 16 + lr] = c1[i] + bi;
    }
  }
  __syncthreads();
  const int row = t >> 3, j = t & 7;
  float s = 0.f, q = 0.f;
#pragma unroll
  for (int i = 0; i < 32; i++) {
    float x = fBuf[row * FPITCH + 256 + j + 8 * i];
    s += x; q += x * x;
  }
  red8(s, q);
  const float mu = s * (1.f / 256.f);
  const float rsv = rsqrtf(q * (1.f / 256.f) - mu * mu + EPS);
#pragma unroll 1
  for (int i = 0; i < 32; i++) {
    const int c = j + 8 * i;
    float x = fBuf[row * FPITCH + 256 + c];
    param_out_ln[(size_t)(r0 + row) * 256 + c] = (x - mu) * rsv * nog[c] + nob[c];
  }
#pragma unroll
  for (int jj = 0; jj < 8; jj++) {
    const int idx4 = jj * 256 + t;
    const int rwq = idx4 >> 6;
    const int c4 = (idx4 & 63) << 2;
    float4 v;
    v.x = fBuf[rwq * FPITCH + c4 + 0];
    v.y = fBuf[rwq * FPITCH + c4 + 1];
    v.z = fBuf[rwq * FPITCH + c4 + 2];
    v.w = fBuf[rwq * FPITCH + c4 + 3];
    *(float4*)&param_in[(size_t)(r0 + rwq) * 256 + c4] = v;
  }
}

extern "C" void kernel_launch(void* const* d_in, const int* in_sizes, int n_in,
                              void* d_out, int out_size, void* d_ws, size_t ws_size,
                              hipStream_t stream) {
  const float* uf   = (const float*)d_in[0];
  const float* inf  = (const float*)d_in[1];
  const float* dynW = (const float*)d_in[2];
  const float* dynb = (const float*)d_in[3];
  const float* inpW = (const float*)d_in[4];
  const float* inpb = (const float*)d_in[5];
  const float* igW  = (const float*)d_in[6];
  const float* igb  = (const float*)d_in[7];
  const float* ugW  = (const float*)d_in[8];
  const float* ugb  = (const float*)d_in[9];
  const float* fcW  = (const float*)d_in[10];
  const float* fcb  = (const float*)d_in[11];
  const float* nig  = (const float*)d_in[12];
  const float* nib  = (const float*)d_in[13];
  const float* nog  = (const float*)d_in[14];
  const float* nob  = (const float*)d_in[15];
  const float* iig  = (const float*)d_in[16];
  const float* iib  = (const float*)d_in[17];
  const float* iog  = (const float*)d_in[18];
  const float* iob  = (const float*)d_in[19];
  const float* fng  = (const float*)d_in[20];
  const float* fnb  = (const float*)d_in[21];
  float* out = (float*)d_out;

  char* ws = (char*)d_ws;
  unsigned short* Wf = (unsigned short*)ws;
  unsigned short* dynWf = Wf;
  unsigned short* inpWf = Wf + 131072;
  unsigned short* igWf  = Wf + 262144;
  unsigned short* ugWf  = Wf + 327680;
  unsigned short* fcWf  = Wf + 393216;
  float* param_in     = (float*)(ws + (1 << 20));
  float* param_out_ln = (float*)(ws + (1 << 20) + (16 << 20));

  k_cvt_all<<<dim3(1792), dim3(256), 0, stream>>>(dynW, inpW, igW, ugW, fcW, Wf);

  k_params<<<dim3(512), dim3(256), 0, stream>>>(uf, dynWf, dynb, nog, nob,
                                                param_in, param_out_ln);

  k_main<<<dim3(4608), dim3(256), 0, stream>>>(
      inf, inpWf, inpb, igWf, igb, ugWf, ugb, fcWf, fcb,
      nig, nib, iig, iib, iog, iob, fng, fnb,
      param_in, param_out_ln, out);
}

// Round 17
// 255.223 us; speedup vs baseline: 1.2377x; 1.2377x over previous
//
#include <hip/hip_runtime.h>

#define EPS 1e-5f
#define APITCH 264   // bf16 tile row pitch (shorts); 528B rows, 16B-aligned

typedef __attribute__((ext_vector_type(8))) short bf16x8;
typedef __attribute__((ext_vector_type(4))) float f32x4;
typedef __attribute__((ext_vector_type(2))) float f32x2;

// RTNE (one-time weight conversion)
__device__ __forceinline__ unsigned short f2b_rtne(float f) {
  unsigned u = __builtin_bit_cast(unsigned, f);
  u += 0x7fffu + ((u >> 16) & 1u);
  return (unsigned short)(u >> 16);
}
// HW packed f32->2xbf16 (RTNE)
__device__ __forceinline__ unsigned cvt_pk(float lo, float hi) {
  unsigned r;
  asm("v_cvt_pk_bf16_f32 %0, %1, %2" : "=v"(r) : "v"(lo), "v"(hi));
  return r;
}
__device__ __forceinline__ float bhalf(unsigned pk, int hi) {
  unsigned u = hi ? (pk & 0xffff0000u) : (pk << 16);
  return __builtin_bit_cast(float, u);
}
__device__ __forceinline__ int div9(int r) {
  return (int)(__umulhi((unsigned)r, 954437177u) >> 1);
}
// fast sigmoid: v_rcp_f32 (~1ulp) instead of IEEE div chain (~7 VALU ops)
__device__ __forceinline__ float fsig(float x) {
  return __builtin_amdgcn_rcpf(1.f + __expf(-x));
}

// ---- packed f32 math (CDNA dual-FP32 VOP3P) ----
__device__ __forceinline__ f32x2 pk_add(f32x2 a, f32x2 b) {
  f32x2 d; asm("v_pk_add_f32 %0, %1, %2" : "=v"(d) : "v"(a), "v"(b)); return d;
}
__device__ __forceinline__ f32x2 pk_mul(f32x2 a, f32x2 b) {
  f32x2 d; asm("v_pk_mul_f32 %0, %1, %2" : "=v"(d) : "v"(a), "v"(b)); return d;
}
__device__ __forceinline__ f32x2 pk_fma(f32x2 a, f32x2 b, f32x2 c) {
  f32x2 d; asm("v_pk_fma_f32 %0, %1, %2, %3" : "=v"(d) : "v"(a), "v"(b), "v"(c)); return d;
}
__device__ __forceinline__ f32x2 ld2(const float* p) { return *(const f32x2*)p; }

// ---- DPP 16-lane sum reduction (ctrl is a template literal) ----
template <int CTRL>
__device__ __forceinline__ float dppadd(float v) {
  int x = __builtin_amdgcn_update_dpp(0, __builtin_bit_cast(int, v), CTRL, 0xf, 0xf, true);
  return v + __builtin_bit_cast(float, x);
}
__device__ __forceinline__ float dpp_reduce16(float v) {
  v = dppadd<0xB1>(v);    // quad_perm:[1,0,3,2]  (xor 1)
  v = dppadd<0x4E>(v);    // quad_perm:[2,3,0,1]  (xor 2)
  v = dppadd<0x124>(v);   // row_ror:4
  v = dppadd<0x128>(v);   // row_ror:8
  return v;               // every lane in the 16-lane row holds the row sum
}

// Convert all 5 weight matrices into MFMA-fragment-linear bf16 (contiguous dst).
// ig/ug/fc k-index pre-permuted for the pi-packed LDS tiles:
//   pi: col = cb + q*16 + lr  ->  p = cb + lr*4 + q  (within each 64-col block)
__global__ void k_cvt_all(const float* __restrict__ dynW, const float* __restrict__ inpW,
                          const float* __restrict__ igW, const float* __restrict__ ugW,
                          const float* __restrict__ fcW, unsigned short* __restrict__ dst) {
  int i = blockIdx.x * blockDim.x + threadIdx.x;   // [0, 458752)
  const float* src; int off; int perm;
  if (i < 131072)      { src = dynW; off = i;          perm = 0; }
  else if (i < 262144) { src = inpW; off = i - 131072; perm = 0; }
  else if (i < 327680) { src = igW;  off = i - 262144; perm = 1; }
  else if (i < 393216) { src = ugW;  off = i - 327680; perm = 1; }
  else                 { src = fcW;  off = i - 393216; perm = 1; }
  int j = off & 7, lane = (off >> 3) & 63, kk = (off >> 9) & 7, ct = off >> 12;
  int row = ct * 16 + (lane & 15);
  int p = kk * 32 + (lane >> 4) * 8 + j;           // k position in fragment order
  int col = perm ? ((p & ~63) + (p & 3) * 16 + ((p >> 2) & 15)) : p;
  dst[i] = f2b_rtne(src[row * 256 + col]);
}

// ================= 32-row main kernel (R15 structure + rcp sigmoid) =================
// Unified reg budget: 88 arch + 32 AGPR = 120 total (cliff in (144,168]:
// R9/R11/R15 @<=144 -> 22% occ; R6/R16 @168 -> 11.6%). a re-read per q is the
// constrained optimum: R16's a-hold (-85% LDS reads) lost 2x to halved occupancy.
// b[8] burst -> 16 MFMA unchanged (R10: splitting = -33%).

__device__ __forceinline__ void gemmQ(const short* src,
                                      const unsigned short* __restrict__ W,
                                      f32x4 (&acc)[4][2],
                                      int wv, int lane, int lr, int lh) {
#pragma unroll
  for (int q = 0; q < 4; q++) {
    const unsigned short* Wp = W + ((wv * 4 + q) << 12) + lane * 8;
    bf16x8 b[8];
#pragma unroll
    for (int kk = 0; kk < 8; kk++) b[kk] = *(const bf16x8*)&Wp[kk * 512];
    int zoff = 0;
    asm volatile("" : "+v"(zoff));          // opaque 0: forces a re-read each q
    const short* ap = src + zoff;
    bf16x8 a[8];
#pragma unroll
    for (int kk = 0; kk < 8; kk++)
      a[kk] = *(const bf16x8*)&ap[lr * APITCH + kk * 32 + lh * 8];
    acc[q][0] = (f32x4){0.f, 0.f, 0.f, 0.f};
#pragma unroll
    for (int kk = 0; kk < 8; kk++)
      acc[q][0] = __builtin_amdgcn_mfma_f32_16x16x32_bf16(a[kk], b[kk], acc[q][0], 0, 0, 0);
#pragma unroll
    for (int kk = 0; kk < 8; kk++)
      a[kk] = *(const bf16x8*)&ap[(16 + lr) * APITCH + kk * 32 + lh * 8];
    acc[q][1] = (f32x4){0.f, 0.f, 0.f, 0.f};
#pragma unroll
    for (int kk = 0; kk < 8; kk++)
      acc[q][1] = __builtin_amdgcn_mfma_f32_16x16x32_bf16(a[kk], b[kk], acc[q][1], 0, 0, 0);
  }
}

// per-row (sum, sumsq): pk presum over q, DPP 16-lane reduce, one LDS write per row-pair
__device__ __forceinline__ void statsW(const f32x4 (&acc)[4][2], const f32x2 (&b42)[4],
                                       float* sP, float* qP, int wv, int lr, int lh) {
#pragma unroll
  for (int rh = 0; rh < 2; rh++)
#pragma unroll
    for (int p = 0; p < 2; p++) {
      f32x2 s2 = (f32x2){0.f, 0.f}, q2 = (f32x2){0.f, 0.f};
#pragma unroll
      for (int q = 0; q < 4; q++) {
        f32x2 a2 = (f32x2){acc[q][rh][2 * p], acc[q][rh][2 * p + 1]};
        f32x2 t = pk_add(a2, b42[q]);
        s2 = pk_add(s2, t);
        q2 = pk_fma(t, t, q2);
      }
      float s0 = dpp_reduce16(s2[0]);
      float s1 = dpp_reduce16(s2[1]);
      float q0 = dpp_reduce16(q2[0]);
      float q1 = dpp_reduce16(q2[1]);
      if (lr == 0) {
        int r = rh * 16 + lh * 4 + 2 * p;
        sP[wv * 32 + r] = s0;  sP[wv * 32 + r + 1] = s1;
        qP[wv * 32 + r] = q0;  qP[wv * 32 + r + 1] = q1;
      }
    }
}
// cross-wave combine -> (-mu, rs) pairs
__device__ __forceinline__ void statsR(const float* sP, const float* qP,
                                       f32x2 (&nmu)[2][2], f32x2 (&rv)[2][2], int lh) {
#pragma unroll
  for (int rh = 0; rh < 2; rh++)
#pragma unroll
    for (int p = 0; p < 2; p++) {
      int r = rh * 16 + lh * 4 + 2 * p;
      f32x2 S = pk_add(pk_add(ld2(sP + r), ld2(sP + 32 + r)),
                       pk_add(ld2(sP + 64 + r), ld2(sP + 96 + r)));
      f32x2 Q = pk_add(pk_add(ld2(qP + r), ld2(qP + 32 + r)),
                       pk_add(ld2(qP + 64 + r), ld2(qP + 96 + r)));
      float m0 = S[0] * (1.f / 256.f), m1 = S[1] * (1.f / 256.f);
      nmu[rh][p] = (f32x2){-m0, -m1};
      rv[rh][p] = (f32x2){rsqrtf(Q[0] * (1.f / 256.f) - m0 * m0 + EPS),
                          rsqrtf(Q[1] * (1.f / 256.f) - m1 * m1 + EPS)};
    }
}

// NOTE: no min-waves arg — a second __launch_bounds__ argument caps arch-VGPR at
// 256/minwaves on MFMA kernels (observed R2-R4) and forces scratch.
__global__ __launch_bounds__(256) void k_main(
    const float* __restrict__ inf,
    const unsigned short* __restrict__ inpWf, const float* __restrict__ inpb,
    const unsigned short* __restrict__ igWf, const float* __restrict__ igb,
    const unsigned short* __restrict__ ugWf, const float* __restrict__ ugb,
    const unsigned short* __restrict__ fcWf, const float* __restrict__ fcb,
    const float* __restrict__ nig, const float* __restrict__ nib,
    const float* __restrict__ iig, const float* __restrict__ iib,
    const float* __restrict__ iog, const float* __restrict__ iob,
    const float* __restrict__ fng, const float* __restrict__ fnb,
    const float* __restrict__ param_in, const float* __restrict__ param_out_ln,
    float* __restrict__ out) {
  __shared__ short aT[32 * APITCH];
  __shared__ short gT[32 * APITCH];
  __shared__ float sP[2][128], qP[2][128];

  const int t = threadIdx.x;
  const int wv = t >> 6, lane = t & 63, lr = lane & 15, lh = lane >> 4;
  const int cb = wv * 64;
  const int r0 = blockIdx.x * 32;

  // stage 32x256 f32 -> bf16 LDS (coalesced float4 in, packed b64 out)
#pragma unroll
  for (int j = 0; j < 8; j++) {
    const int idx4 = j * 256 + t;
    const int row = idx4 >> 6;
    const int c4 = (idx4 & 63) << 2;
    const float4 v = *(const float4*)&inf[(size_t)(r0 + row) * 256 + c4];
    uint2 pk;
    pk.x = cvt_pk(v.x, v.y);
    pk.y = cvt_pk(v.z, v.w);
    *(uint2*)&aT[row * APITCH + c4] = pk;
  }
  __syncthreads();                              // S1

  f32x4 acc[4][2];
  f32x2 b42[4], ga2[4], be2[4], nmu[2][2], rv[2][2];
  unsigned gio[4][2][2];   // packed bf16 pairs per (q, pair)

  // ---- PH0: input_in -> gate_feats -> gT (pi-layout, packed 8B writes) ----
  gemmQ(aT, inpWf, acc, wv, lane, lr, lh);
#pragma unroll
  for (int q = 0; q < 4; q++) { float b = inpb[cb + q * 16 + lr]; b42[q] = (f32x2){b, b}; }
#pragma unroll
  for (int rh = 0; rh < 2; rh++)
#pragma unroll
    for (int p = 0; p < 2; p++) {
      const int rrA = rh * 16 + lh * 4 + 2 * p;
      const float* pin0 = param_in + (size_t)div9(r0 + rrA) * 256;
      const float* pin1 = param_in + (size_t)div9(r0 + rrA + 1) * 256;
      float gAv[4], gBv[4];
#pragma unroll
      for (int q = 0; q < 4; q++) {
        f32x2 a2 = (f32x2){acc[q][rh][2 * p], acc[q][rh][2 * p + 1]};
        f32x2 tt = pk_add(a2, b42[q]);
        gAv[q] = tt[0] * pin0[cb + q * 16 + lr];
        gBv[q] = tt[1] * pin1[cb + q * 16 + lr];
      }
      uint2 pkA, pkB;
      pkA.x = cvt_pk(gAv[0], gAv[1]); pkA.y = cvt_pk(gAv[2], gAv[3]);
      pkB.x = cvt_pk(gBv[0], gBv[1]); pkB.y = cvt_pk(gBv[2], gBv[3]);
      *(uint2*)&gT[rrA * APITCH + cb + lr * 4] = pkA;
      *(uint2*)&gT[(rrA + 1) * APITCH + cb + lr * 4] = pkB;
    }

  // ---- PH1: input_out, LN -> gio ----
  gemmQ(aT, inpWf + (16 << 12), acc, wv, lane, lr, lh);
#pragma unroll
  for (int q = 0; q < 4; q++) { float b = inpb[256 + cb + q * 16 + lr]; b42[q] = (f32x2){b, b}; }
  statsW(acc, b42, sP[1], qP[1], wv, lr, lh);
  __syncthreads();                              // S2: gT + stats published
  statsR(sP[1], qP[1], nmu, rv, lh);
#pragma unroll
  for (int q = 0; q < 4; q++) {
    float g = iog[cb + q * 16 + lr], e = iob[cb + q * 16 + lr];
    ga2[q] = (f32x2){g, g}; be2[q] = (f32x2){e, e};
  }
#pragma unroll
  for (int q = 0; q < 4; q++)
#pragma unroll
    for (int rh = 0; rh < 2; rh++)
#pragma unroll
      for (int p = 0; p < 2; p++) {
        f32x2 a2 = (f32x2){acc[q][rh][2 * p], acc[q][rh][2 * p + 1]};
        f32x2 tt = pk_add(pk_add(a2, b42[q]), nmu[rh][p]);
        f32x2 v2 = pk_fma(pk_mul(tt, rv[rh][p]), ga2[q], be2[q]);
        gio[q][rh][p] = cvt_pk(v2[0], v2[1]);
      }

  // ---- PH2: ig gate on gT; gio <- g1 * ioLN ----
  gemmQ(gT, igWf, acc, wv, lane, lr, lh);
#pragma unroll
  for (int q = 0; q < 4; q++) { float b = igb[cb + q * 16 + lr]; b42[q] = (f32x2){b, b}; }
  statsW(acc, b42, sP[0], qP[0], wv, lr, lh);
  __syncthreads();                              // S3
  statsR(sP[0], qP[0], nmu, rv, lh);
#pragma unroll
  for (int q = 0; q < 4; q++) {
    float g = iig[cb + q * 16 + lr], e = iib[cb + q * 16 + lr];
    ga2[q] = (f32x2){g, g}; be2[q] = (f32x2){e, e};
  }
#pragma unroll
  for (int q = 0; q < 4; q++)
#pragma unroll
    for (int rh = 0; rh < 2; rh++)
#pragma unroll
      for (int p = 0; p < 2; p++) {
        f32x2 a2 = (f32x2){acc[q][rh][2 * p], acc[q][rh][2 * p + 1]};
        f32x2 tt = pk_add(pk_add(a2, b42[q]), nmu[rh][p]);
        f32x2 p2 = pk_fma(pk_mul(tt, rv[rh][p]), ga2[q], be2[q]);
        float g10 = fsig(p2[0]);
        float g11 = fsig(p2[1]);
        unsigned w = gio[q][rh][p];
        gio[q][rh][p] = cvt_pk(g10 * bhalf(w, 0), g11 * bhalf(w, 1));
      }

  // ---- PH3: ug gate on gT; features = g2*param_out_ln + gio -> aT (pi) ----
  gemmQ(gT, ugWf, acc, wv, lane, lr, lh);
#pragma unroll
  for (int q = 0; q < 4; q++) { float b = ugb[cb + q * 16 + lr]; b42[q] = (f32x2){b, b}; }
  statsW(acc, b42, sP[1], qP[1], wv, lr, lh);
  __syncthreads();                              // S4
  statsR(sP[1], qP[1], nmu, rv, lh);
#pragma unroll
  for (int q = 0; q < 4; q++) {
    float g = nig[cb + q * 16 + lr], e = nib[cb + q * 16 + lr];
    ga2[q] = (f32x2){g, g}; be2[q] = (f32x2){e, e};
  }
#pragma unroll
  for (int rh = 0; rh < 2; rh++)
#pragma unroll
    for (int p = 0; p < 2; p++) {
      const int rrA = rh * 16 + lh * 4 + 2 * p;
      const float* po0 = param_out_ln + (size_t)div9(r0 + rrA) * 256;
      const float* po1 = param_out_ln + (size_t)div9(r0 + rrA + 1) * 256;
      float fA[4], fB[4];
#pragma unroll
      for (int q = 0; q < 4; q++) {
        f32x2 a2 = (f32x2){acc[q][rh][2 * p], acc[q][rh][2 * p + 1]};
        f32x2 tt = pk_add(pk_add(a2, b42[q]), nmu[rh][p]);
        f32x2 u2 = pk_fma(pk_mul(tt, rv[rh][p]), ga2[q], be2[q]);
        float g20 = fsig(u2[0]);
        float g21 = fsig(u2[1]);
        unsigned w = gio[q][rh][p];
        fA[q] = g20 * po0[cb + q * 16 + lr] + bhalf(w, 0);
        fB[q] = g21 * po1[cb + q * 16 + lr] + bhalf(w, 1);
      }
      uint2 pkA, pkB;
      pkA.x = cvt_pk(fA[0], fA[1]); pkA.y = cvt_pk(fA[2], fA[3]);
      pkB.x = cvt_pk(fB[0], fB[1]); pkB.y = cvt_pk(fB[2], fB[3]);
      *(uint2*)&aT[rrA * APITCH + cb + lr * 4] = pkA;
      *(uint2*)&aT[(rrA + 1) * APITCH + cb + lr * 4] = pkB;
    }
  __syncthreads();                              // S5: features published in aT

  // ---- PH4: fc (pi-permuted weights), LN, relu -> out ----
  gemmQ(aT, fcWf, acc, wv, lane, lr, lh);
#pragma unroll
  for (int q = 0; q < 4; q++) { float b = fcb[cb + q * 16 + lr]; b42[q] = (f32x2){b, b}; }
  statsW(acc, b42, sP[0], qP[0], wv, lr, lh);
  __syncthreads();                              // S6
  statsR(sP[0], qP[0], nmu, rv, lh);
#pragma unroll
  for (int q = 0; q < 4; q++) {
    float g = fng[cb + q * 16 + lr], e = fnb[cb + q * 16 + lr];
    ga2[q] = (f32x2){g, g}; be2[q] = (f32x2){e, e};
  }
#pragma unroll
  for (int q = 0; q < 4; q++) {
    const int col = cb + q * 16 + lr;
#pragma unroll
    for (int rh = 0; rh < 2; rh++)
#pragma unroll
      for (int p = 0; p < 2; p++) {
        f32x2 a2 = (f32x2){acc[q][rh][2 * p], acc[q][rh][2 * p + 1]};
        f32x2 tt = pk_add(pk_add(a2, b42[q]), nmu[rh][p]);
        f32x2 v2 = pk_fma(pk_mul(tt, rv[rh][p]), ga2[q], be2[q]);
        const int rrA = r0 + rh * 16 + lh * 4 + 2 * p;
        out[(size_t)rrA * 256 + col] = fmaxf(v2[0], 0.f);
        out[(size_t)(rrA + 1) * 256 + col] = fmaxf(v2[1], 0.f);
      }
  }
}

// ================= kernel 1: params (unchanged) =================
#define FPITCH 516

__device__ __forceinline__ void red8(float& s, float& q) {
#pragma unroll
  for (int m = 1; m < 8; m <<= 1) { s += __shfl_xor(s, m); q += __shfl_xor(q, m); }
}

__global__ __launch_bounds__(256) void k_params(
    const float* __restrict__ uf, const unsigned short* __restrict__ dynWf,
    const float* __restrict__ dynb, const float* __restrict__ nog,
    const float* __restrict__ nob, float* __restrict__ param_in,
    float* __restrict__ param_out_ln) {
  __shared__ short aT[32 * APITCH];
  __shared__ float fBuf[32 * FPITCH];
  const int t = threadIdx.x;
  const int wv = t >> 6, lane = t & 63, lr = lane & 15, lh = lane >> 4;
  const int r0 = blockIdx.x * 32;
#pragma unroll
  for (int j = 0; j < 8; j++) {
    const int idx4 = j * 256 + t;
    const int row = idx4 >> 6;
    const int c4 = (idx4 & 63) << 2;
    const float4 v = *(const float4*)&uf[(size_t)(r0 + row) * 256 + c4];
    uint2 pk;
    pk.x = cvt_pk(v.x, v.y);
    pk.y = cvt_pk(v.z, v.w);
    *(uint2*)&aT[row * APITCH + c4] = pk;
  }
  __syncthreads();
  bf16x8 a0[8], a1[8];
#pragma unroll
  for (int kk = 0; kk < 8; kk++) {
    a0[kk] = *(const bf16x8*)&aT[lr * APITCH + kk * 32 + lh * 8];
    a1[kk] = *(const bf16x8*)&aT[(16 + lr) * APITCH + kk * 32 + lh * 8];
  }
#pragma unroll 1
  for (int cp = 0; cp < 8; cp++) {
    const int ct = wv * 8 + cp;
    bf16x8 b[8];
#pragma unroll
    for (int kk = 0; kk < 8; kk++)
      b[kk] = *(const bf16x8*)&dynWf[((ct * 8 + kk) * 64 + lane) * 8];
    const float bi = dynb[ct * 16 + lr];
    f32x4 c0 = {0.f, 0.f, 0.f, 0.f}, c1 = c0;
#pragma unroll
    for (int kk = 0; kk < 8; kk++) {
      c0 = __builtin_amdgcn_mfma_f32_16x16x32_bf16(a0[kk], b[kk], c0, 0, 0, 0);
      c1 = __builtin_amdgcn_mfma_f32_16x16x32_bf16(a1[kk], b[kk], c1, 0, 0, 0);
    }
#pragma unroll
    for (int i = 0; i < 4; i++) {
      fBuf[(lh * 4 + i) * FPITCH + ct * 16 + lr] = c0[i] + bi;
      fBuf[(16 + lh * 4 + i) * FPITCH + ct * 16 + lr] = c1[i] + bi;
    }
  }
  __syncthreads();
  const int row = t >> 3, j = t & 7;
  float s = 0.f, q = 0.f;
#pragma unroll
  for (int i = 0; i < 32; i++) {
    float x = fBuf[row * FPITCH + 256 + j + 8 * i];
    s += x; q += x * x;
  }
  red8(s, q);
  const float mu = s * (1.f / 256.f);
  const float rsv = rsqrtf(q * (1.f / 256.f) - mu * mu + EPS);
#pragma unroll 1
  for (int i = 0; i < 32; i++) {
    const int c = j + 8 * i;
    float x = fBuf[row * FPITCH + 256 + c];
    param_out_ln[(size_t)(r0 + row) * 256 + c] = (x - mu) * rsv * nog[c] + nob[c];
  }
#pragma unroll
  for (int jj = 0; jj < 8; jj++) {
    const int idx4 = jj * 256 + t;
    const int rwq = idx4 >> 6;
    const int c4 = (idx4 & 63) << 2;
    float4 v;
    v.x = fBuf[rwq * FPITCH + c4 + 0];
    v.y = fBuf[rwq * FPITCH + c4 + 1];
    v.z = fBuf[rwq * FPITCH + c4 + 2];
    v.w = fBuf[rwq * FPITCH + c4 + 3];
    *(float4*)&param_in[(size_t)(r0 + rwq) * 256 + c4] = v;
  }
}

extern "C" void kernel_launch(void* const* d_in, const int* in_sizes, int n_in,
                              void* d_out, int out_size, void* d_ws, size_t ws_size,
                              hipStream_t stream) {
  const float* uf   = (const float*)d_in[0];
  const float* inf  = (const float*)d_in[1];
  const float* dynW = (const float*)d_in[2];
  const float* dynb = (const float*)d_in[3];
  const float* inpW = (const float*)d_in[4];
  const float* inpb = (const float*)d_in[5];
  const float* igW  = (const float*)d_in[6];
  const float* igb  = (const float*)d_in[7];
  const float* ugW  = (const float*)d_in[8];
  const float* ugb  = (const float*)d_in[9];
  const float* fcW  = (const float*)d_in[10];
  const float* fcb  = (const float*)d_in[11];
  const float* nig  = (const float*)d_in[12];
  const float* nib  = (const float*)d_in[13];
  const float* nog  = (const float*)d_in[14];
  const float* nob  = (const float*)d_in[15];
  const float* iig  = (const float*)d_in[16];
  const float* iib  = (const float*)d_in[17];
  const float* iog  = (const float*)d_in[18];
  const float* iob  = (const float*)d_in[19];
  const float* fng  = (const float*)d_in[20];
  const float* fnb  = (const float*)d_in[21];
  float* out = (float*)d_out;

  char* ws = (char*)d_ws;
  unsigned short* Wf = (unsigned short*)ws;
  unsigned short* dynWf = Wf;
  unsigned short* inpWf = Wf + 131072;
  unsigned short* igWf  = Wf + 262144;
  unsigned short* ugWf  = Wf + 327680;
  unsigned short* fcWf  = Wf + 393216;
  float* param_in     = (float*)(ws + (1 << 20));
  float* param_out_ln = (float*)(ws + (1 << 20) + (16 << 20));

  k_cvt_all<<<dim3(1792), dim3(256), 0, stream>>>(dynW, inpW, igW, ugW, fcW, Wf);

  k_params<<<dim3(512), dim3(256), 0, stream>>>(uf, dynWf, dynb, nog, nob,
                                                param_in, param_out_ln);

  k_main<<<dim3(4608), dim3(256), 0, stream>>>(
      inf, inpWf, inpb, igWf, igb, ugWf, ugb, fcWf, fcb,
      nig, nib, iig, iib, iog, iob, fng, fnb,
      param_in, param_out_ln, out);
}

// Round 19
// 252.330 us; speedup vs baseline: 1.2519x; 1.0115x over previous
//
#include <hip/hip_runtime.h>

#define EPS 1e-5f
#define APITCH 264   // k_params-only row pitch (shorts)

typedef __attribute__((ext_vector_type(8))) short bf16x8;
typedef __attribute__((ext_vector_type(4))) float f32x4;
typedef __attribute__((ext_vector_type(2))) float f32x2;

// RTNE (one-time weight conversion)
__device__ __forceinline__ unsigned short f2b_rtne(float f) {
  unsigned u = __builtin_bit_cast(unsigned, f);
  u += 0x7fffu + ((u >> 16) & 1u);
  return (unsigned short)(u >> 16);
}
// HW packed f32->2xbf16 (RTNE)
__device__ __forceinline__ unsigned cvt_pk(float lo, float hi) {
  unsigned r;
  asm("v_cvt_pk_bf16_f32 %0, %1, %2" : "=v"(r) : "v"(lo), "v"(hi));
  return r;
}
__device__ __forceinline__ float bhalf(unsigned pk, int hi) {
  unsigned u = hi ? (pk & 0xffff0000u) : (pk << 16);
  return __builtin_bit_cast(float, u);
}
__device__ __forceinline__ int div9(int r) {
  return (int)(__umulhi((unsigned)r, 954437177u) >> 1);
}
// fast sigmoid: v_rcp_f32 (~1ulp) instead of IEEE div chain
__device__ __forceinline__ float fsig(float x) {
  return __builtin_amdgcn_rcpf(1.f + __expf(-x));
}

// ---- packed f32 math (CDNA dual-FP32 VOP3P) ----
__device__ __forceinline__ f32x2 pk_add(f32x2 a, f32x2 b) {
  f32x2 d; asm("v_pk_add_f32 %0, %1, %2" : "=v"(d) : "v"(a), "v"(b)); return d;
}
__device__ __forceinline__ f32x2 pk_mul(f32x2 a, f32x2 b) {
  f32x2 d; asm("v_pk_mul_f32 %0, %1, %2" : "=v"(d) : "v"(a), "v"(b)); return d;
}
__device__ __forceinline__ f32x2 pk_fma(f32x2 a, f32x2 b, f32x2 c) {
  f32x2 d; asm("v_pk_fma_f32 %0, %1, %2, %3" : "=v"(d) : "v"(a), "v"(b), "v"(c)); return d;
}
__device__ __forceinline__ f32x2 ld2(const float* p) { return *(const f32x2*)p; }

// ---- DPP 16-lane sum reduction ----
template <int CTRL>
__device__ __forceinline__ float dppadd(float v) {
  int x = __builtin_amdgcn_update_dpp(0, __builtin_bit_cast(int, v), CTRL, 0xf, 0xf, true);
  return v + __builtin_bit_cast(float, x);
}
__device__ __forceinline__ float dpp_reduce16(float v) {
  v = dppadd<0xB1>(v);    // quad_perm:[1,0,3,2]
  v = dppadd<0x4E>(v);    // quad_perm:[2,3,0,1]
  v = dppadd<0x124>(v);   // row_ror:4
  v = dppadd<0x128>(v);   // row_ror:8
  return v;
}

// Convert all 5 weight matrices into MFMA-fragment-linear bf16 (contiguous dst).
// ig/ug/fc k-index pre-permuted by pi^{-1} to match the fragment-linear gate/
// feature tiles: pi(64wv+16q+lr) = (2wv+(lr>>3))*32 + ((lr>>1)&3)*8 + (lr&1)*4 + q.
__global__ void k_cvt_all(const float* __restrict__ dynW, const float* __restrict__ inpW,
                          const float* __restrict__ igW, const float* __restrict__ ugW,
                          const float* __restrict__ fcW, unsigned short* __restrict__ dst) {
  int i = blockIdx.x * blockDim.x + threadIdx.x;   // [0, 458752)
  const float* src; int off; int perm;
  if (i < 131072)      { src = dynW; off = i;          perm = 0; }
  else if (i < 262144) { src = inpW; off = i - 131072; perm = 0; }
  else if (i < 327680) { src = igW;  off = i - 262144; perm = 1; }
  else if (i < 393216) { src = ugW;  off = i - 327680; perm = 1; }
  else                 { src = fcW;  off = i - 393216; perm = 1; }
  int j = off & 7, lane = (off >> 3) & 63, kk = (off >> 9) & 7, ct = off >> 12;
  int row = ct * 16 + (lane & 15);
  int p = kk * 32 + (lane >> 4) * 8 + j;           // k position in fragment order
  int col;
  if (perm) {
    int q = p & 3, b0 = (p >> 2) & 1, lh4 = (p >> 3) & 3, kkp = p >> 5;
    col = (kkp >> 1) * 64 + q * 16 + (kkp & 1) * 8 + lh4 * 2 + b0;   // pi^{-1}(p)
  } else {
    col = p;
  }
  dst[i] = f2b_rtne(src[row * 256 + col]);
}

// ================= 32-row main kernel: FRAGMENT-LINEAR activation tiles =============
// aT/gT stored fragment-linear (16KB each = 2 halves x 4096 shorts): a-frag read for
// lane l, half h, frag kk is shorts[h*4096 + kk*512 + l*8] -> wave-contiguous
// 16B/lane, bank-conflict-free by construction (same layout trick as the weights).
// fidx(r,p) = (r>>4)*4096 + ((p>>5)*64 + (r&15) + ((p>>3)&3)*16)*8 + (p&7).
// (R18's bug: half-stride written as 8192 -> out-of-bounds aliasing; fixed to 4096.)
// Reg budget: 88 arch + 32 AGPR = 120 (cliff in (144,168]); b[8] burst unchanged.

__device__ __forceinline__ void gemmQ(const short* src,
                                      const unsigned short* __restrict__ W,
                                      f32x4 (&acc)[4][2],
                                      int wv, int lane) {
#pragma unroll
  for (int q = 0; q < 4; q++) {
    const unsigned short* Wp = W + ((wv * 4 + q) << 12) + lane * 8;
    bf16x8 b[8];
#pragma unroll
    for (int kk = 0; kk < 8; kk++) b[kk] = *(const bf16x8*)&Wp[kk * 512];
    int zoff = 0;
    asm volatile("" : "+v"(zoff));          // opaque 0: forces a re-read each q
    const short* ap = src + zoff + lane * 8;
    bf16x8 a[8];
#pragma unroll
    for (int kk = 0; kk < 8; kk++)
      a[kk] = *(const bf16x8*)&ap[kk * 512];
    acc[q][0] = (f32x4){0.f, 0.f, 0.f, 0.f};
#pragma unroll
    for (int kk = 0; kk < 8; kk++)
      acc[q][0] = __builtin_amdgcn_mfma_f32_16x16x32_bf16(a[kk], b[kk], acc[q][0], 0, 0, 0);
#pragma unroll
    for (int kk = 0; kk < 8; kk++)
      a[kk] = *(const bf16x8*)&ap[4096 + kk * 512];
    acc[q][1] = (f32x4){0.f, 0.f, 0.f, 0.f};
#pragma unroll
    for (int kk = 0; kk < 8; kk++)
      acc[q][1] = __builtin_amdgcn_mfma_f32_16x16x32_bf16(a[kk], b[kk], acc[q][1], 0, 0, 0);
  }
}

// per-row (sum, sumsq): pk presum over q, DPP 16-lane reduce, LDS write per row-pair
__device__ __forceinline__ void statsW(const f32x4 (&acc)[4][2], const f32x2 (&b42)[4],
                                       float* sP, float* qP, int wv, int lr, int lh) {
#pragma unroll
  for (int rh = 0; rh < 2; rh++)
#pragma unroll
    for (int p = 0; p < 2; p++) {
      f32x2 s2 = (f32x2){0.f, 0.f}, q2 = (f32x2){0.f, 0.f};
#pragma unroll
      for (int q = 0; q < 4; q++) {
        f32x2 a2 = (f32x2){acc[q][rh][2 * p], acc[q][rh][2 * p + 1]};
        f32x2 t = pk_add(a2, b42[q]);
        s2 = pk_add(s2, t);
        q2 = pk_fma(t, t, q2);
      }
      float s0 = dpp_reduce16(s2[0]);
      float s1 = dpp_reduce16(s2[1]);
      float q0 = dpp_reduce16(q2[0]);
      float q1 = dpp_reduce16(q2[1]);
      if (lr == 0) {
        int r = rh * 16 + lh * 4 + 2 * p;
        sP[wv * 32 + r] = s0;  sP[wv * 32 + r + 1] = s1;
        qP[wv * 32 + r] = q0;  qP[wv * 32 + r + 1] = q1;
      }
    }
}
// cross-wave combine -> (-mu, rs) pairs
__device__ __forceinline__ void statsR(const float* sP, const float* qP,
                                       f32x2 (&nmu)[2][2], f32x2 (&rv)[2][2], int lh) {
#pragma unroll
  for (int rh = 0; rh < 2; rh++)
#pragma unroll
    for (int p = 0; p < 2; p++) {
      int r = rh * 16 + lh * 4 + 2 * p;
      f32x2 S = pk_add(pk_add(ld2(sP + r), ld2(sP + 32 + r)),
                       pk_add(ld2(sP + 64 + r), ld2(sP + 96 + r)));
      f32x2 Q = pk_add(pk_add(ld2(qP + r), ld2(qP + 32 + r)),
                       pk_add(ld2(qP + 64 + r), ld2(qP + 96 + r)));
      float m0 = S[0] * (1.f / 256.f), m1 = S[1] * (1.f / 256.f);
      nmu[rh][p] = (f32x2){-m0, -m1};
      rv[rh][p] = (f32x2){rsqrtf(Q[0] * (1.f / 256.f) - m0 * m0 + EPS),
                          rsqrtf(Q[1] * (1.f / 256.f) - m1 * m1 + EPS)};
    }
}

// NOTE: no min-waves arg — a second __launch_bounds__ argument caps arch-VGPR at
// 256/minwaves on MFMA kernels (observed R2-R4) and forces scratch.
__global__ __launch_bounds__(256) void k_main(
    const float* __restrict__ inf,
    const unsigned short* __restrict__ inpWf, const float* __restrict__ inpb,
    const unsigned short* __restrict__ igWf, const float* __restrict__ igb,
    const unsigned short* __restrict__ ugWf, const float* __restrict__ ugb,
    const unsigned short* __restrict__ fcWf, const float* __restrict__ fcb,
    const float* __restrict__ nig, const float* __restrict__ nib,
    const float* __restrict__ iig, const float* __restrict__ iib,
    const float* __restrict__ iog, const float* __restrict__ iob,
    const float* __restrict__ fng, const float* __restrict__ fnb,
    const float* __restrict__ param_in, const float* __restrict__ param_out_ln,
    float* __restrict__ out) {
  __shared__ short aT[32 * 256];   // fragment-linear, 16KB (2 x 4096-short halves)
  __shared__ short gT[32 * 256];   // fragment-linear, 16KB
  __shared__ float sP[2][128], qP[2][128];

  const int t = threadIdx.x;
  const int wv = t >> 6, lane = t & 63, lr = lane & 15, lh = lane >> 4;
  const int cb = wv * 64;
  const int r0 = blockIdx.x * 32;

  // stage 32x256 f32 -> bf16 fragment-linear LDS
#pragma unroll
  for (int j = 0; j < 8; j++) {
    const int idx4 = j * 256 + t;
    const int row = idx4 >> 6;
    const int c4 = (idx4 & 63) << 2;
    const float4 v = *(const float4*)&inf[(size_t)(r0 + row) * 256 + c4];
    uint2 pk;
    pk.x = cvt_pk(v.x, v.y);
    pk.y = cvt_pk(v.z, v.w);
    const int sa = (row >> 4) * 4096 +
                   (((c4 >> 5) * 64) + (row & 15) + ((c4 >> 3) & 3) * 16) * 8 + (c4 & 7);
    *(uint2*)&aT[sa] = pk;
  }
  __syncthreads();                              // S1

  f32x4 acc[4][2];
  f32x2 b42[4], ga2[4], be2[4], nmu[2][2], rv[2][2];
  unsigned gio[4][2][2];   // packed bf16 pairs per (q, pair)

  // pi-write base components for this thread (gate/feature epilogue stores)
  const int kkp = 2 * wv + (lr >> 3);
  const int lh4 = (lr >> 1) & 3;
  const int jb = (lr & 1) * 4;

  // ---- PH0: input_in -> gate_feats -> gT (pi fragment-linear, 2x 8B writes) ----
  gemmQ(aT, inpWf, acc, wv, lane);
#pragma unroll
  for (int q = 0; q < 4; q++) { float b = inpb[cb + q * 16 + lr]; b42[q] = (f32x2){b, b}; }
#pragma unroll
  for (int rh = 0; rh < 2; rh++)
#pragma unroll
    for (int p = 0; p < 2; p++) {
      const int rrA = rh * 16 + lh * 4 + 2 * p;
      const float* pin0 = param_in + (size_t)div9(r0 + rrA) * 256;
      const float* pin1 = param_in + (size_t)div9(r0 + rrA + 1) * 256;
      float gAv[4], gBv[4];
#pragma unroll
      for (int q = 0; q < 4; q++) {
        f32x2 a2 = (f32x2){acc[q][rh][2 * p], acc[q][rh][2 * p + 1]};
        f32x2 tt = pk_add(a2, b42[q]);
        gAv[q] = tt[0] * pin0[cb + q * 16 + lr];
        gBv[q] = tt[1] * pin1[cb + q * 16 + lr];
      }
      uint2 pkA, pkB;
      pkA.x = cvt_pk(gAv[0], gAv[1]); pkA.y = cvt_pk(gAv[2], gAv[3]);
      pkB.x = cvt_pk(gBv[0], gBv[1]); pkB.y = cvt_pk(gBv[2], gBv[3]);
      const int base = rh * 4096 + (kkp * 64 + lh * 4 + 2 * p + lh4 * 16) * 8 + jb;
      *(uint2*)&gT[base] = pkA;
      *(uint2*)&gT[base + 8] = pkB;
    }

  // ---- PH1: input_out, LN -> gio ----
  gemmQ(aT, inpWf + (16 << 12), acc, wv, lane);
#pragma unroll
  for (int q = 0; q < 4; q++) { float b = inpb[256 + cb + q * 16 + lr]; b42[q] = (f32x2){b, b}; }
  statsW(acc, b42, sP[1], qP[1], wv, lr, lh);
  __syncthreads();                              // S2: gT + stats published
  statsR(sP[1], qP[1], nmu, rv, lh);
#pragma unroll
  for (int q = 0; q < 4; q++) {
    float g = iog[cb + q * 16 + lr], e = iob[cb + q * 16 + lr];
    ga2[q] = (f32x2){g, g}; be2[q] = (f32x2){e, e};
  }
#pragma unroll
  for (int q = 0; q < 4; q++)
#pragma unroll
    for (int rh = 0; rh < 2; rh++)
#pragma unroll
      for (int p = 0; p < 2; p++) {
        f32x2 a2 = (f32x2){acc[q][rh][2 * p], acc[q][rh][2 * p + 1]};
        f32x2 tt = pk_add(pk_add(a2, b42[q]), nmu[rh][p]);
        f32x2 v2 = pk_fma(pk_mul(tt, rv[rh][p]), ga2[q], be2[q]);
        gio[q][rh][p] = cvt_pk(v2[0], v2[1]);
      }

  // ---- PH2: ig gate on gT; gio <- g1 * ioLN ----
  gemmQ(gT, igWf, acc, wv, lane);
#pragma unroll
  for (int q = 0; q < 4; q++) { float b = igb[cb + q * 16 + lr]; b42[q] = (f32x2){b, b}; }
  statsW(acc, b42, sP[0], qP[0], wv, lr, lh);
  __syncthreads();                              // S3
  statsR(sP[0], qP[0], nmu, rv, lh);
#pragma unroll
  for (int q = 0; q < 4; q++) {
    float g = iig[cb + q * 16 + lr], e = iib[cb + q * 16 + lr];
    ga2[q] = (f32x2){g, g}; be2[q] = (f32x2){e, e};
  }
#pragma unroll
  for (int q = 0; q < 4; q++)
#pragma unroll
    for (int rh = 0; rh < 2; rh++)
#pragma unroll
      for (int p = 0; p < 2; p++) {
        f32x2 a2 = (f32x2){acc[q][rh][2 * p], acc[q][rh][2 * p + 1]};
        f32x2 tt = pk_add(pk_add(a2, b42[q]), nmu[rh][p]);
        f32x2 p2 = pk_fma(pk_mul(tt, rv[rh][p]), ga2[q], be2[q]);
        float g10 = fsig(p2[0]);
        float g11 = fsig(p2[1]);
        unsigned w = gio[q][rh][p];
        gio[q][rh][p] = cvt_pk(g10 * bhalf(w, 0), g11 * bhalf(w, 1));
      }

  // ---- PH3: ug gate on gT; features = g2*param_out_ln + gio -> aT (pi frag) ----
  gemmQ(gT, ugWf, acc, wv, lane);
#pragma unroll
  for (int q = 0; q < 4; q++) { float b = ugb[cb + q * 16 + lr]; b42[q] = (f32x2){b, b}; }
  statsW(acc, b42, sP[1], qP[1], wv, lr, lh);
  __syncthreads();                              // S4
  statsR(sP[1], qP[1], nmu, rv, lh);
#pragma unroll
  for (int q = 0; q < 4; q++) {
    float g = nig[cb + q * 16 + lr], e = nib[cb + q * 16 + lr];
    ga2[q] = (f32x2){g, g}; be2[q] = (f32x2){e, e};
  }
#pragma unroll
  for (int rh = 0; rh < 2; rh++)
#pragma unroll
    for (int p = 0; p < 2; p++) {
      const int rrA = rh * 16 + lh * 4 + 2 * p;
      const float* po0 = param_out_ln + (size_t)div9(r0 + rrA) * 256;
      const float* po1 = param_out_ln + (size_t)div9(r0 + rrA + 1) * 256;
      float fA[4], fB[4];
#pragma unroll
      for (int q = 0; q < 4; q++) {
        f32x2 a2 = (f32x2){acc[q][rh][2 * p], acc[q][rh][2 * p + 1]};
        f32x2 tt = pk_add(pk_add(a2, b42[q]), nmu[rh][p]);
        f32x2 u2 = pk_fma(pk_mul(tt, rv[rh][p]), ga2[q], be2[q]);
        float g20 = fsig(u2[0]);
        float g21 = fsig(u2[1]);
        unsigned w = gio[q][rh][p];
        fA[q] = g20 * po0[cb + q * 16 + lr] + bhalf(w, 0);
        fB[q] = g21 * po1[cb + q * 16 + lr] + bhalf(w, 1);
      }
      uint2 pkA, pkB;
      pkA.x = cvt_pk(fA[0], fA[1]); pkA.y = cvt_pk(fA[2], fA[3]);
      pkB.x = cvt_pk(fB[0], fB[1]); pkB.y = cvt_pk(fB[2], fB[3]);
      const int base = rh * 4096 + (kkp * 64 + lh * 4 + 2 * p + lh4 * 16) * 8 + jb;
      *(uint2*)&aT[base] = pkA;
      *(uint2*)&aT[base + 8] = pkB;
    }
  __syncthreads();                              // S5: features published in aT

  // ---- PH4: fc (pi-permuted weights), LN, relu -> out ----
  gemmQ(aT, fcWf, acc, wv, lane);
#pragma unroll
  for (int q = 0; q < 4; q++) { float b = fcb[cb + q * 16 + lr]; b42[q] = (f32x2){b, b}; }
  statsW(acc, b42, sP[0], qP[0], wv, lr, lh);
  __syncthreads();                              // S6
  statsR(sP[0], qP[0], nmu, rv, lh);
#pragma unroll
  for (int q = 0; q < 4; q++) {
    float g = fng[cb + q * 16 + lr], e = fnb[cb + q * 16 + lr];
    ga2[q] = (f32x2){g, g}; be2[q] = (f32x2){e, e};
  }
#pragma unroll
  for (int q = 0; q < 4; q++) {
    const int col = cb + q * 16 + lr;
#pragma unroll
    for (int rh = 0; rh < 2; rh++)
#pragma unroll
      for (int p = 0; p < 2; p++) {
        f32x2 a2 = (f32x2){acc[q][rh][2 * p], acc[q][rh][2 * p + 1]};
        f32x2 tt = pk_add(pk_add(a2, b42[q]), nmu[rh][p]);
        f32x2 v2 = pk_fma(pk_mul(tt, rv[rh][p]), ga2[q], be2[q]);
        const int rrA = r0 + rh * 16 + lh * 4 + 2 * p;
        out[(size_t)rrA * 256 + col] = fmaxf(v2[0], 0.f);
        out[(size_t)(rrA + 1) * 256 + col] = fmaxf(v2[1], 0.f);
      }
  }
}

// ================= kernel 1: params (unchanged, row-major private layout) ===========
#define FPITCH 516

__device__ __forceinline__ void red8(float& s, float& q) {
#pragma unroll
  for (int m = 1; m < 8; m <<= 1) { s += __shfl_xor(s, m); q += __shfl_xor(q, m); }
}

__global__ __launch_bounds__(256) void k_params(
    const float* __restrict__ uf, const unsigned short* __restrict__ dynWf,
    const float* __restrict__ dynb, const float* __restrict__ nog,
    const float* __restrict__ nob, float* __restrict__ param_in,
    float* __restrict__ param_out_ln) {
  __shared__ short aT[32 * APITCH];
  __shared__ float fBuf[32 * FPITCH];
  const int t = threadIdx.x;
  const int wv = t >> 6, lane = t & 63, lr = lane & 15, lh = lane >> 4;
  const int r0 = blockIdx.x * 32;
#pragma unroll
  for (int j = 0; j < 8; j++) {
    const int idx4 = j * 256 + t;
    const int row = idx4 >> 6;
    const int c4 = (idx4 & 63) << 2;
    const float4 v = *(const float4*)&uf[(size_t)(r0 + row) * 256 + c4];
    uint2 pk;
    pk.x = cvt_pk(v.x, v.y);
    pk.y = cvt_pk(v.z, v.w);
    *(uint2*)&aT[row * APITCH + c4] = pk;
  }
  __syncthreads();
  bf16x8 a0[8], a1[8];
#pragma unroll
  for (int kk = 0; kk < 8; kk++) {
    a0[kk] = *(const bf16x8*)&aT[lr * APITCH + kk * 32 + lh * 8];
    a1[kk] = *(const bf16x8*)&aT[(16 + lr) * APITCH + kk * 32 + lh * 8];
  }
#pragma unroll 1
  for (int cp = 0; cp < 8; cp++) {
    const int ct = wv * 8 + cp;
    bf16x8 b[8];
#pragma unroll
    for (int kk = 0; kk < 8; kk++)
      b[kk] = *(const bf16x8*)&dynWf[((ct * 8 + kk) * 64 + lane) * 8];
    const float bi = dynb[ct * 16 + lr];
    f32x4 c0 = {0.f, 0.f, 0.f, 0.f}, c1 = c0;
#pragma unroll
    for (int kk = 0; kk < 8; kk++) {
      c0 = __builtin_amdgcn_mfma_f32_16x16x32_bf16(a0[kk], b[kk], c0, 0, 0, 0);
      c1 = __builtin_amdgcn_mfma_f32_16x16x32_bf16(a1[kk], b[kk], c1, 0, 0, 0);
    }
#pragma unroll
    for (int i = 0; i < 4; i++) {
      fBuf[(lh * 4 + i) * FPITCH + ct * 16 + lr] = c0[i] + bi;
      fBuf[(16 + lh * 4 + i) * FPITCH + ct * 16 + lr] = c1[i] + bi;
    }
  }
  __syncthreads();
  const int row = t >> 3, j = t & 7;
  float s = 0.f, q = 0.f;
#pragma unroll
  for (int i = 0; i < 32; i++) {
    float x = fBuf[row * FPITCH + 256 + j + 8 * i];
    s += x; q += x * x;
  }
  red8(s, q);
  const float mu = s * (1.f / 256.f);
  const float rsv = rsqrtf(q * (1.f / 256.f) - mu * mu + EPS);
#pragma unroll 1
  for (int i = 0; i < 32; i++) {
    const int c = j + 8 * i;
    float x = fBuf[row * FPITCH + 256 + c];
    param_out_ln[(size_t)(r0 + row) * 256 + c] = (x - mu) * rsv * nog[c] + nob[c];
  }
#pragma unroll
  for (int jj = 0; jj < 8; jj++) {
    const int idx4 = jj * 256 + t;
    const int rwq = idx4 >> 6;
    const int c4 = (idx4 & 63) << 2;
    float4 v;
    v.x = fBuf[rwq * FPITCH + c4 + 0];
    v.y = fBuf[rwq * FPITCH + c4 + 1];
    v.z = fBuf[rwq * FPITCH + c4 + 2];
    v.w = fBuf[rwq * FPITCH + c4 + 3];
    *(float4*)&param_in[(size_t)(r0 + rwq) * 256 + c4] = v;
  }
}

extern "C" void kernel_launch(void* const* d_in, const int* in_sizes, int n_in,
                              void* d_out, int out_size, void* d_ws, size_t ws_size,
                              hipStream_t stream) {
  const float* uf   = (const float*)d_in[0];
  const float* inf  = (const float*)d_in[1];
  const float* dynW = (const float*)d_in[2];
  const float* dynb = (const float*)d_in[3];
  const float* inpW = (const float*)d_in[4];
  const float* inpb = (const float*)d_in[5];
  const float* igW  = (const float*)d_in[6];
  const float* igb  = (const float*)d_in[7];
  const float* ugW  = (const float*)d_in[8];
  const float* ugb  = (const float*)d_in[9];
  const float* fcW  = (const float*)d_in[10];
  const float* fcb  = (const float*)d_in[11];
  const float* nig  = (const float*)d_in[12];
  const float* nib  = (const float*)d_in[13];
  const float* nog  = (const float*)d_in[14];
  const float* nob  = (const float*)d_in[15];
  const float* iig  = (const float*)d_in[16];
  const float* iib  = (const float*)d_in[17];
  const float* iog  = (const float*)d_in[18];
  const float* iob  = (const float*)d_in[19];
  const float* fng  = (const float*)d_in[20];
  const float* fnb  = (const float*)d_in[21];
  float* out = (float*)d_out;

  char* ws = (char*)d_ws;
  unsigned short* Wf = (unsigned short*)ws;
  unsigned short* dynWf = Wf;
  unsigned short* inpWf = Wf + 131072;
  unsigned short* igWf  = Wf + 262144;
  unsigned short* ugWf  = Wf + 327680;
  unsigned short* fcWf  = Wf + 393216;
  float* param_in     = (float*)(ws + (1 << 20));
  float* param_out_ln = (float*)(ws + (1 << 20) + (16 << 20));

  k_cvt_all<<<dim3(1792), dim3(256), 0, stream>>>(dynW, inpW, igW, ugW, fcW, Wf);

  k_params<<<dim3(512), dim3(256), 0, stream>>>(uf, dynWf, dynb, nog, nob,
                                                param_in, param_out_ln);

  k_main<<<dim3(4608), dim3(256), 0, stream>>>(
      inf, inpWf, inpb, igWf, igb, ugWf, ugb, fcWf, fcb,
      nig, nib, iig, iib, iog, iob, fng, fnb,
      param_in, param_out_ln, out);
}